// Round 1
// baseline (37093.640 us; speedup 1.0000x reference)
//
#include <hip/hip_runtime.h>
#include <hip/hip_cooperative_groups.h>
#include <math.h>

namespace cg = cooperative_groups;

#define T_  256
#define B_  256
#define I_  256
#define H_  512
#define NWG 256
#define NTH 512
#define KCH 64
#define PITCH 260                       // LDS row pitch in floats (bank-spread, 16B-aligned)
#define SMEM_FLOATS (2*KCH*PITCH + 12*B_)

__device__ __forceinline__ float sig_(float v){ return 1.0f/(1.0f+__expf(-v)); }

__global__ __launch_bounds__(NTH, 1)
void qlstm_kernel(
    const float* __restrict__ x,
    const float* __restrict__ Wf_l, const float* __restrict__ bf_l,
    const float* __restrict__ Wf_p, const float* __restrict__ bf_p,
    const float* __restrict__ Wf_r,
    const float* __restrict__ Wi_l, const float* __restrict__ bi_l,
    const float* __restrict__ Wi_p, const float* __restrict__ bi_p,
    const float* __restrict__ Wi_r,
    const float* __restrict__ Wg_l, const float* __restrict__ bg_l,
    const float* __restrict__ Wg_p, const float* __restrict__ bg_p,
    const float* __restrict__ Wg_r,
    const float* __restrict__ Wo_l, const float* __restrict__ bo_l,
    const float* __restrict__ Wo_p, const float* __restrict__ bo_p,
    const float* __restrict__ Wo_r,
    float* __restrict__ out,
    float* __restrict__ ws)
{
  extern __shared__ float smem[];                  // [2][KCH][PITCH] hx chunks + accx[12][B_]
  float* accx = smem + 2*KCH*PITCH;

  const int tid  = threadIdx.x;                    // 0..511
  const int w    = blockIdx.x;                     // 0..255
  const int b    = tid & (B_-1);
  const int half = __builtin_amdgcn_readfirstlane(tid >> 8);  // wave-uniform 0/1
  const int h0   = w * 2;

  float* hxbuf = ws;                               // [2][H_][B_]  ping-pong state(t)
  float* cxbuf = ws + 2*H_*B_;                     // [H_][B_]
  float* sx    = ws + 3*H_*B_;                     // [T_][4][B_]  input-side scalars

  // ---- one-time: sx[t=w][n][b] = x[t,b,:] . Wl_n[0,:I] + bl_n[0] ; zero-init state ----
  if (tid < B_) {
    const float* xrow = x + ((size_t)w*B_ + tid)*I_;
    float a0=0.f, a1=0.f, a2=0.f, a3=0.f;
    #pragma unroll 8
    for (int i = 0; i < I_; i += 4) {
      float4 v = *(const float4*)(xrow + i);
      a0 += v.x*Wf_l[i] + v.y*Wf_l[i+1] + v.z*Wf_l[i+2] + v.w*Wf_l[i+3];
      a1 += v.x*Wi_l[i] + v.y*Wi_l[i+1] + v.z*Wi_l[i+2] + v.w*Wi_l[i+3];
      a2 += v.x*Wg_l[i] + v.y*Wg_l[i+1] + v.z*Wg_l[i+2] + v.w*Wg_l[i+3];
      a3 += v.x*Wo_l[i] + v.y*Wo_l[i+1] + v.z*Wo_l[i+2] + v.w*Wo_l[i+3];
    }
    sx[((size_t)w*4+0)*B_ + tid] = a0 + bf_l[0];
    sx[((size_t)w*4+1)*B_ + tid] = a1 + bi_l[0];
    sx[((size_t)w*4+2)*B_ + tid] = a2 + bg_l[0];
    sx[((size_t)w*4+3)*B_ + tid] = a3 + bo_l[0];
  }
  hxbuf[h0*B_ + tid] = 0.f;                        // rows h0, h0+1 of ping-0 (512 floats)
  cxbuf[h0*B_ + tid] = 0.f;

  // ---- per-thread 6 GEMM rows (wave-uniform -> scalar weight loads) ----
  // half0: Wf_r[h0],Wf_r[h0+1],Wi_r[h0],Wi_r[h0+1],Wg_r[h0],Wg_r[h0+1]   (accx rows 0..5)
  // half1: Wo_r[h0],Wo_r[h0+1],Wlh_f,Wlh_i,Wlh_g,Wlh_o                   (accx rows 6..11)
  const float *r0,*r1,*r2,*r3,*r4,*r5;
  if (half == 0) {
    r0 = Wf_r + (size_t)h0*H_;  r1 = Wf_r + (size_t)(h0+1)*H_;
    r2 = Wi_r + (size_t)h0*H_;  r3 = Wi_r + (size_t)(h0+1)*H_;
    r4 = Wg_r + (size_t)h0*H_;  r5 = Wg_r + (size_t)(h0+1)*H_;
  } else {
    r0 = Wo_r + (size_t)h0*H_;  r1 = Wo_r + (size_t)(h0+1)*H_;
    r2 = Wf_l + I_;  r3 = Wi_l + I_;  r4 = Wg_l + I_;  r5 = Wo_l + I_;
  }

  cg::grid_group grid = cg::this_grid();
  __threadfence();
  grid.sync();

  int cur = 0;
  for (int t = 0; t < T_; ++t) {
    const float* __restrict__ hxr = hxbuf + (size_t)cur*H_*B_;   // state(t), [k][b]
    float acc0=0.f, acc1=0.f, acc2=0.f, acc3=0.f, acc4=0.f, acc5=0.f;

    // stage chunk 0 into buf0
    {
      float* dst = smem;
      #pragma unroll
      for (int s = 0; s < 8; ++s) {
        int q   = tid + s*NTH;                     // 0..4095 float4s
        int row = q >> 6;
        int col = (q & 63) * 4;
        float4 v = *(const float4*)(hxr + (size_t)row*B_ + col);
        *(float4*)(dst + row*PITCH + col) = v;
      }
    }
    __syncthreads();

    for (int c = 0; c < 8; ++c) {
      float* bufc = smem + (c & 1)*(KCH*PITCH);
      if (c < 7) {                                 // prefetch next chunk into other buffer
        float* dst = smem + ((c+1) & 1)*(KCH*PITCH);
        const float* srcb = hxr + (size_t)(c+1)*KCH*B_;
        #pragma unroll
        for (int s = 0; s < 8; ++s) {
          int q   = tid + s*NTH;
          int row = q >> 6;
          int col = (q & 63) * 4;
          float4 v = *(const float4*)(srcb + (size_t)row*B_ + col);
          *(float4*)(dst + row*PITCH + col) = v;
        }
      }
      const int koff = c*KCH;
      #pragma unroll 8
      for (int kk = 0; kk < KCH; ++kk) {
        float xv = bufc[kk*PITCH + b];             // stride-1 across lanes: conflict-free
        acc0 += r0[koff+kk]*xv;  acc1 += r1[koff+kk]*xv;
        acc2 += r2[koff+kk]*xv;  acc3 += r3[koff+kk]*xv;
        acc4 += r4[koff+kk]*xv;  acc5 += r5[koff+kk]*xv;
      }
      // coalesced ys[t-1][w][:] writes: extract column b=w of state(t) from LDS
      if (t > 0 && tid < KCH) {
        out[((size_t)(t-1)*B_ + w)*H_ + koff + tid] = bufc[tid*PITCH + w];
      }
      __syncthreads();
    }

    // exchange accumulators across halves
    accx[(half*6+0)*B_ + b] = acc0;
    accx[(half*6+1)*B_ + b] = acc1;
    accx[(half*6+2)*B_ + b] = acc2;
    accx[(half*6+3)*B_ + b] = acc3;
    accx[(half*6+4)*B_ + b] = acc4;
    accx[(half*6+5)*B_ + b] = acc5;
    __syncthreads();

    // epilogue: gates, cell update, state write
    {
      const int hi = tid >> 8;                     // 0/1
      const int hh = h0 + hi;
      float q0 = cosf(sx[((size_t)t*4+0)*B_ + b] + accx[(8+0)*B_ + b]);
      float q1 = cosf(sx[((size_t)t*4+1)*B_ + b] + accx[(8+1)*B_ + b]);
      float q2 = cosf(sx[((size_t)t*4+2)*B_ + b] + accx[(8+2)*B_ + b]);
      float q3 = cosf(sx[((size_t)t*4+3)*B_ + b] + accx[(8+3)*B_ + b]);
      float fg = sig_ (q0*Wf_p[hh] + bf_p[hh]) + accx[(0*2+hi)*B_ + b];
      float ig = sig_ (q1*Wi_p[hh] + bi_p[hh]) + accx[(1*2+hi)*B_ + b];
      float gg = tanhf(q2*Wg_p[hh] + bg_p[hh]) + accx[(2*2+hi)*B_ + b];
      float og = sig_ (q3*Wo_p[hh] + bo_p[hh]) + accx[(3*2+hi)*B_ + b];
      float cold = cxbuf[(size_t)hh*B_ + b];
      float cnew = fg*cold + ig*gg;
      float hnew = og*tanhf(cnew);
      cxbuf[(size_t)hh*B_ + b] = cnew;
      hxbuf[(size_t)(cur^1)*H_*B_ + (size_t)hh*B_ + b] = hnew;
      if (t == T_-1) {                             // ys[255] + final hx, cx
        out[((size_t)t*B_ + b)*H_ + hh] = hnew;
        out[(size_t)T_*B_*H_ + (size_t)b*H_ + hh] = hnew;
        out[(size_t)T_*B_*H_ + (size_t)B_*H_ + (size_t)b*H_ + hh] = cnew;
      }
    }
    cur ^= 1;
    __threadfence();
    grid.sync();
  }
}

extern "C" void kernel_launch(void* const* d_in, const int* in_sizes, int n_in,
                              void* d_out, int out_size, void* d_ws, size_t ws_size,
                              hipStream_t stream) {
  const float* x    = (const float*)d_in[0];
  const float* Wf_l = (const float*)d_in[1];  const float* bf_l = (const float*)d_in[2];
  const float* Wf_p = (const float*)d_in[3];  const float* bf_p = (const float*)d_in[4];
  const float* Wf_r = (const float*)d_in[5];
  const float* Wi_l = (const float*)d_in[6];  const float* bi_l = (const float*)d_in[7];
  const float* Wi_p = (const float*)d_in[8];  const float* bi_p = (const float*)d_in[9];
  const float* Wi_r = (const float*)d_in[10];
  const float* Wg_l = (const float*)d_in[11]; const float* bg_l = (const float*)d_in[12];
  const float* Wg_p = (const float*)d_in[13]; const float* bg_p = (const float*)d_in[14];
  const float* Wg_r = (const float*)d_in[15];
  const float* Wo_l = (const float*)d_in[16]; const float* bo_l = (const float*)d_in[17];
  const float* Wo_p = (const float*)d_in[18]; const float* bo_p = (const float*)d_in[19];
  const float* Wo_r = (const float*)d_in[20];
  float* out = (float*)d_out;
  float* wsf = (float*)d_ws;

  void* args[] = { &x,
                   &Wf_l, &bf_l, &Wf_p, &bf_p, &Wf_r,
                   &Wi_l, &bi_l, &Wi_p, &bi_p, &Wi_r,
                   &Wg_l, &bg_l, &Wg_p, &bg_p, &Wg_r,
                   &Wo_l, &bo_l, &Wo_p, &bo_p, &Wo_r,
                   &out, &wsf };
  hipLaunchCooperativeKernel((void*)qlstm_kernel, dim3(NWG), dim3(NTH),
                             args, (unsigned)(SMEM_FLOATS*sizeof(float)), stream);
}

// Round 2
// 17890.160 us; speedup vs baseline: 2.0734x; 2.0734x over previous
//
#include <hip/hip_runtime.h>
#include <hip/hip_cooperative_groups.h>
#include <math.h>

namespace cg = cooperative_groups;

#define T_ 256
#define B_ 256
#define I_ 256
#define H_ 512
#define NB 8          // batch groups
#define NH 32         // h-group WGs per batch group
#define BG 32         // batches per group
#define NTH 512

typedef __attribute__((ext_vector_type(8))) short short8;
typedef __attribute__((ext_vector_type(4))) float f32x4;

__device__ __forceinline__ float sig_(float v){ return 1.0f/(1.0f+__expf(-v)); }
__device__ __forceinline__ short f2bf(float f){            // fp32 -> bf16 RTNE
  unsigned u = __float_as_uint(f);
  unsigned r = (u + 0x7fffu + ((u>>16)&1u)) >> 16;
  return (short)r;
}

__global__ __launch_bounds__(NTH)
void qlstm_kernel(
    const float* __restrict__ x,
    const float* __restrict__ Wf_l, const float* __restrict__ bf_l,
    const float* __restrict__ Wf_p, const float* __restrict__ bf_p,
    const float* __restrict__ Wf_r,
    const float* __restrict__ Wi_l, const float* __restrict__ bi_l,
    const float* __restrict__ Wi_p, const float* __restrict__ bi_p,
    const float* __restrict__ Wi_r,
    const float* __restrict__ Wg_l, const float* __restrict__ bg_l,
    const float* __restrict__ Wg_p, const float* __restrict__ bg_p,
    const float* __restrict__ Wg_r,
    const float* __restrict__ Wo_l, const float* __restrict__ bo_l,
    const float* __restrict__ Wo_p, const float* __restrict__ bo_p,
    const float* __restrict__ Wo_r,
    float* __restrict__ out,
    char* __restrict__ wsb)
{
  // LDS: hx tile (bf16, XOR-swizzled rows) + gate-acc exchange + q scalars
  __shared__ char  hxT[32*1024];        // [32 b][512 k] bf16, 1 KiB rows
  __shared__ float gacc[4*32*17];       // [gate][b][hl(+pad)]
  __shared__ float qd[4*32];            // hx-side q dots
  __shared__ float qcs[4*32];           // cos(sx + qd)

  float*          sx  = (float*)wsb;                       // [T][4][B] fp32 (1 MiB)
  unsigned short* hxg = (unsigned short*)(wsb + 1048576);  // [B][H] bf16 (256 KiB)
  unsigned*       cnt = (unsigned*)(wsb + 1572864);        // [T][NB] one-shot barriers

  const int tid  = threadIdx.x;
  const int wgid = blockIdx.x;
  const int bgp  = wgid & 7;            // batch group (bid%8 -> same XCD heuristic)
  const int nh   = wgid >> 3;           // h group 0..31
  const int wave = tid >> 6;
  const int l    = tid & 63;
  const int l15  = l & 15;
  const int q4   = l >> 4;
  const int m    = wave & 3;            // gate tile (f,i,g,o)
  const int n    = wave >> 2;           // batch half
  const bool hasq = (m == 0);           // waves 0,4 also run the q-row tile

  // ---------------- init (once) ----------------
  // sx[t][g][b] = x . Wl[0,:I] + bl[0] for this WG's (t-slice, batch-group)
  for (int idx = tid; idx < 8*4*BG; idx += NTH) {
    int g   = idx >> 8;
    int rem = idx & 255;
    int tt  = rem >> 5;
    int b   = rem & 31;
    int t   = nh*8 + tt;
    int bglob = bgp*BG + b;
    const float* wl = (g==0)?Wf_l:(g==1)?Wi_l:(g==2)?Wg_l:Wo_l;
    const float* bl = (g==0)?bf_l:(g==1)?bi_l:(g==2)?bg_l:bo_l;
    const float* xr = x + ((size_t)t*B_ + bglob)*I_;
    float a = 0.f;
    #pragma unroll 8
    for (int i2 = 0; i2 < I_; i2 += 4) {
      float4 v = *(const float4*)(xr + i2);
      a += v.x*wl[i2] + v.y*wl[i2+1] + v.z*wl[i2+2] + v.w*wl[i2+3];
    }
    sx[((size_t)t*4 + g)*B_ + bglob] = a + bl[0];
  }
  // zero this group's barrier slots (t in nh*8..nh*8+8)
  if (tid < 8) cnt[(nh*8 + tid)*8 + bgp] = 0;

  // A-fragments (weights) -> bf16 registers, once.
  // Layout for mfma_f32_16x16x32_bf16: lane holds A[row=l&15][k = 8*(l>>4)+e]
  short8 afrag[16];
  short8 afragq[16];
  {
    const float* wr = (m==0)?Wf_r:(m==1)?Wi_r:(m==2)?Wg_r:Wo_r;
    const int h = nh*16 + l15;
    #pragma unroll
    for (int kk = 0; kk < 16; ++kk) {
      const float* src = wr + (size_t)h*H_ + kk*32 + q4*8;
      short8 pk;
      #pragma unroll
      for (int j = 0; j < 8; ++j) pk[j] = f2bf(src[j]);
      afrag[kk] = pk;
    }
    if (hasq) {
      #pragma unroll
      for (int kk = 0; kk < 16; ++kk) {
        short8 pk;
        if (l15 < 4) {
          const float* ql = (l15==0)?Wf_l:(l15==1)?Wi_l:(l15==2)?Wg_l:Wo_l;
          const float* src = ql + I_ + kk*32 + q4*8;
          #pragma unroll
          for (int j = 0; j < 8; ++j) pk[j] = f2bf(src[j]);
        } else {
          #pragma unroll
          for (int j = 0; j < 8; ++j) pk[j] = 0;
        }
        afragq[kk] = pk;
      }
    }
  }

  // epilogue ownership: thread (hl = tid&15, eb = tid>>4) owns (b, h); cx in reg
  const int hl = tid & 15;
  const int eb = tid >> 4;
  const int h_ep = nh*16 + hl;
  const int bglob_ep = bgp*BG + eb;
  const float wfp = Wf_p[h_ep], bfp = bf_p[h_ep];
  const float wip = Wi_p[h_ep], bip = bi_p[h_ep];
  const float wgp = Wg_p[h_ep], bgp_ = bg_p[h_ep];
  const float wop = Wo_p[h_ep], bop = bo_p[h_ep];
  float cxr = 0.f;

  cg::grid_group grid = cg::this_grid();
  __threadfence();
  grid.sync();                          // ONE full-grid sync (sx + barrier-slot init)

  // B-frag addressing constants (XOR-swizzled LDS reads)
  const int bb   = n*16 + l15;          // batch row in hxT
  const int brow = bb * 1024;
  const int bsw  = (bb & 7) << 4;
  const int bq16 = q4 * 16;

  for (int t = 0; t < T_; ++t) {
    // ---- [A] stage hx tile: global bf16 (linear, coalesced) -> LDS (swizzled write) ----
    if (t == 0) {
      #pragma unroll
      for (int i = 0; i < 4; ++i)
        *(f32x4*)(hxT + ((wave*4+i)*1024 + 16*l)) = (f32x4){0.f,0.f,0.f,0.f};
    } else {
      #pragma unroll
      for (int i = 0; i < 4; ++i) {
        const int b = wave*4 + i;       // wave-uniform row
        const char* src = (const char*)hxg + (((size_t)(bgp*BG + b)) << 10) + 16*l;
        short8 v = *(const short8*)src;
        *(short8*)(hxT + (b*1024 + ((16*l) ^ ((b&7)<<4)))) = v;
      }
    }
    __syncthreads();

    // ---- [B] MFMA K-loop: 16 iters, A in regs, B from swizzled LDS ----
    f32x4 acc  = {0.f,0.f,0.f,0.f};
    f32x4 accq = {0.f,0.f,0.f,0.f};
    #pragma unroll
    for (int kk = 0; kk < 16; ++kk) {
      short8 bf = *(const short8*)(hxT + brow + ((kk*64 + bq16) ^ bsw));
      acc = __builtin_amdgcn_mfma_f32_16x16x32_bf16(afrag[kk], bf, acc, 0, 0, 0);
      if (hasq)
        accq = __builtin_amdgcn_mfma_f32_16x16x32_bf16(afragq[kk], bf, accq, 0, 0, 0);
    }
    {
      // C layout: col = l&15 (batch), row = 4*(l>>4)+r (h-local)
      const int cb = n*16 + l15;
      const int r0 = q4*4;
      #pragma unroll
      for (int r = 0; r < 4; ++r)
        gacc[(m*32 + cb)*17 + r0 + r] = acc[r];
      if (hasq && q4 == 0) {
        #pragma unroll
        for (int r = 0; r < 4; ++r)
          qd[r*32 + cb] = accq[r];      // rows 0..3 = gates f,i,g,o
      }
    }
    __syncthreads();

    // ---- [C] q = cos(sx + hx.Wlh), once per (gate,batch) ----
    if (tid < 128) {
      int g = tid >> 5, b = tid & 31;
      float sv = sx[((size_t)t*4 + g)*B_ + bgp*BG + b];
      qcs[g*32 + b] = cosf(sv + qd[g*32 + b]);
    }
    __syncthreads();

    // ---- [D] epilogue: gates, cell update, outputs ----
    {
      float ga = gacc[(0*32 + eb)*17 + hl];
      float gi = gacc[(1*32 + eb)*17 + hl];
      float gg = gacc[(2*32 + eb)*17 + hl];
      float go = gacc[(3*32 + eb)*17 + hl];
      float fv = sig_ (qcs[0*32+eb]*wfp + bfp ) + ga;
      float iv = sig_ (qcs[1*32+eb]*wip + bip ) + gi;
      float gv = tanhf(qcs[2*32+eb]*wgp + bgp_) + gg;
      float ov = sig_ (qcs[3*32+eb]*wop + bop ) + go;
      cxr = fv*cxr + iv*gv;
      float hnew = ov * tanhf(cxr);
      out[((size_t)t*B_ + bglob_ep)*H_ + h_ep] = hnew;
      hxg[(size_t)bglob_ep*H_ + h_ep] = (unsigned short)f2bf(hnew);
      if (t == T_-1) {
        out[(size_t)T_*B_*H_ + (size_t)bglob_ep*H_ + h_ep] = hnew;
        out[(size_t)T_*B_*H_ + (size_t)B_*H_ + (size_t)bglob_ep*H_ + h_ep] = cxr;
      }
    }

    // ---- [E] per-batch-group barrier (32 WGs, one-shot counter per step) ----
    if (t < T_-1) {
      __threadfence();                  // release hxg writes
      __syncthreads();
      if (tid == 0) {
        unsigned* c = &cnt[t*8 + bgp];
        atomicAdd(c, 1u);
        while (atomicAdd(c, 0u) < NH) __builtin_amdgcn_s_sleep(2);
      }
      __syncthreads();
      __threadfence();                  // acquire before next stage
    }
  }
}

extern "C" void kernel_launch(void* const* d_in, const int* in_sizes, int n_in,
                              void* d_out, int out_size, void* d_ws, size_t ws_size,
                              hipStream_t stream) {
  const float* x    = (const float*)d_in[0];
  const float* Wf_l = (const float*)d_in[1];  const float* bf_l = (const float*)d_in[2];
  const float* Wf_p = (const float*)d_in[3];  const float* bf_p = (const float*)d_in[4];
  const float* Wf_r = (const float*)d_in[5];
  const float* Wi_l = (const float*)d_in[6];  const float* bi_l = (const float*)d_in[7];
  const float* Wi_p = (const float*)d_in[8];  const float* bi_p = (const float*)d_in[9];
  const float* Wi_r = (const float*)d_in[10];
  const float* Wg_l = (const float*)d_in[11]; const float* bg_l = (const float*)d_in[12];
  const float* Wg_p = (const float*)d_in[13]; const float* bg_p = (const float*)d_in[14];
  const float* Wg_r = (const float*)d_in[15];
  const float* Wo_l = (const float*)d_in[16]; const float* bo_l = (const float*)d_in[17];
  const float* Wo_p = (const float*)d_in[18]; const float* bo_p = (const float*)d_in[19];
  const float* Wo_r = (const float*)d_in[20];
  float* out = (float*)d_out;
  char*  wsb = (char*)d_ws;

  void* args[] = { &x,
                   &Wf_l, &bf_l, &Wf_p, &bf_p, &Wf_r,
                   &Wi_l, &bi_l, &Wi_p, &bi_p, &Wi_r,
                   &Wg_l, &bg_l, &Wg_p, &bg_p, &Wg_r,
                   &Wo_l, &bo_l, &Wo_p, &bo_p, &Wo_r,
                   &out, &wsb };
  hipLaunchCooperativeKernel((void*)qlstm_kernel, dim3(NB*NH), dim3(NTH),
                             args, 0, stream);
}

// Round 3
// 1196.022 us; speedup vs baseline: 31.0142x; 14.9581x over previous
//
#include <hip/hip_runtime.h>
#include <hip/hip_cooperative_groups.h>
#include <math.h>

namespace cg = cooperative_groups;

#define T_ 256
#define B_ 256
#define I_ 256
#define H_ 512
#define NB 8          // batch groups
#define NH 32         // h-group WGs per batch group
#define BG 32         // batches per group
#define NTH 512

typedef __attribute__((ext_vector_type(8))) short short8;
typedef __attribute__((ext_vector_type(4))) float f32x4;
typedef __attribute__((ext_vector_type(4))) unsigned int uint4v;

__device__ __forceinline__ float sig_(float v){ return 1.0f/(1.0f+__expf(-v)); }
__device__ __forceinline__ short f2bf(float f){            // fp32 -> bf16 RTNE
  unsigned u = __float_as_uint(f);
  unsigned r = (u + 0x7fffu + ((u>>16)&1u)) >> 16;
  return (short)r;
}

__global__ __launch_bounds__(NTH)
void qlstm_kernel(
    const float* __restrict__ x,
    const float* __restrict__ Wf_l, const float* __restrict__ bf_l,
    const float* __restrict__ Wf_p, const float* __restrict__ bf_p,
    const float* __restrict__ Wf_r,
    const float* __restrict__ Wi_l, const float* __restrict__ bi_l,
    const float* __restrict__ Wi_p, const float* __restrict__ bi_p,
    const float* __restrict__ Wi_r,
    const float* __restrict__ Wg_l, const float* __restrict__ bg_l,
    const float* __restrict__ Wg_p, const float* __restrict__ bg_p,
    const float* __restrict__ Wg_r,
    const float* __restrict__ Wo_l, const float* __restrict__ bo_l,
    const float* __restrict__ Wo_p, const float* __restrict__ bo_p,
    const float* __restrict__ Wo_r,
    float* __restrict__ out,
    char* __restrict__ wsb)
{
  __shared__ char  hxT[32*1024];        // [32 b][512 k] bf16, XOR-swizzled rows
  __shared__ float gacc[4*32*17];       // [gate][b][hl(+pad)]
  __shared__ float qd[4*32];            // hx-side q dots per (gate,b)
  __shared__ unsigned short hxe[32*16]; // epilogue hnew staging [b][hl] bf16

  float*          sx    = (float*)wsb;                              // 1 MiB
  unsigned short* hxg   = (unsigned short*)(wsb + (1u<<20));        // [B][H] bf16, LLC-only
  unsigned*       flags = (unsigned*)(wsb + (1u<<20) + (256u<<10)); // [T][NB][32] one-shot

  const int tid  = threadIdx.x;
  const int wgid = blockIdx.x;
  const int bgp  = wgid & 7;            // batch group (== XCD heuristic)
  const int nh   = wgid >> 3;           // h group 0..31
  const int wave = tid >> 6;
  const int l    = tid & 63;
  const int l15  = l & 15;
  const int q4   = l >> 4;
  const int m    = wave & 3;            // gate tile (f,i,g,o)
  const int n    = wave >> 2;           // batch half
  const bool hasq = (m == 0);

  // ---------------- init (once) ----------------
  for (int idx = tid; idx < 8*4*BG; idx += NTH) {
    int g   = idx >> 8;
    int rem = idx & 255;
    int tt  = rem >> 5;
    int b   = rem & 31;
    int t   = nh*8 + tt;
    int bglob = bgp*BG + b;
    const float* wl = (g==0)?Wf_l:(g==1)?Wi_l:(g==2)?Wg_l:Wo_l;
    const float* bl = (g==0)?bf_l:(g==1)?bi_l:(g==2)?bg_l:bo_l;
    const float* xr = x + ((size_t)t*B_ + bglob)*I_;
    float a = 0.f;
    #pragma unroll 8
    for (int i2 = 0; i2 < I_; i2 += 4) {
      float4 v = *(const float4*)(xr + i2);
      a += v.x*wl[i2] + v.y*wl[i2+1] + v.z*wl[i2+2] + v.w*wl[i2+3];
    }
    sx[((size_t)t*4 + g)*B_ + bglob] = a + bl[0];
  }
  // zero this WG's flag for every step (system-scope: lands in LLC, replay-safe)
  if (tid < T_)
    __hip_atomic_store(&flags[((size_t)tid*8 + bgp)*32 + nh], 0u,
                       __ATOMIC_RELAXED, __HIP_MEMORY_SCOPE_SYSTEM);

  // A-fragments (weights) -> bf16 registers, once.
  short8 afrag[16];
  short8 afragq[16];
  {
    const float* wr = (m==0)?Wf_r:(m==1)?Wi_r:(m==2)?Wg_r:Wo_r;
    const int h = nh*16 + l15;
    #pragma unroll
    for (int kk = 0; kk < 16; ++kk) {
      const float* src = wr + (size_t)h*H_ + kk*32 + q4*8;
      short8 pk;
      #pragma unroll
      for (int j = 0; j < 8; ++j) pk[j] = f2bf(src[j]);
      afrag[kk] = pk;
    }
    if (hasq) {
      #pragma unroll
      for (int kk = 0; kk < 16; ++kk) {
        short8 pk;
        if (l15 < 4) {
          const float* ql = (l15==0)?Wf_l:(l15==1)?Wi_l:(l15==2)?Wg_l:Wo_l;
          const float* src = ql + I_ + kk*32 + q4*8;
          #pragma unroll
          for (int j = 0; j < 8; ++j) pk[j] = f2bf(src[j]);
        } else {
          #pragma unroll
          for (int j = 0; j < 8; ++j) pk[j] = 0;
        }
        afragq[kk] = pk;
      }
    }
  }

  // epilogue ownership: (hl = tid&15 -> h, eb = tid>>4 -> b); cx in register
  const int hl = tid & 15;
  const int eb = tid >> 4;
  const int h_ep = nh*16 + hl;
  const int bglob_ep = bgp*BG + eb;
  const float wfp = Wf_p[h_ep], bfp = bf_p[h_ep];
  const float wip = Wi_p[h_ep], bip = bi_p[h_ep];
  const float wgp = Wg_p[h_ep], bgp_ = bg_p[h_ep];
  const float wop = Wo_p[h_ep], bop = bo_p[h_ep];
  float cxr = 0.f;

  cg::grid_group grid = cg::this_grid();
  grid.sync();                          // publishes sx + flag zeroing device-wide

  const int bb   = n*16 + l15;
  const int brow = bb * 1024;
  const int bsw  = (bb & 7) << 4;
  const int bq16 = q4 * 16;

  for (int t = 0; t < T_; ++t) {
    // ---- [A] stage hx: LLC (sc0 sc1) -> LDS swizzled ----
    if (t == 0) {
      #pragma unroll
      for (int i = 0; i < 4; ++i)
        *(f32x4*)(hxT + ((wave*4+i)*1024 + 16*l)) = (f32x4){0.f,0.f,0.f,0.f};
    } else {
      uint4v v0, v1, v2, v3;
      unsigned long long base =
        (unsigned long long)((const char*)hxg + (((size_t)(bgp*BG + wave*4)) << 10) + 16*l);
      asm volatile("global_load_dwordx4 %0, %1, off sc0 sc1"             : "=v"(v0) : "v"(base) : "memory");
      asm volatile("global_load_dwordx4 %0, %1, off offset:1024 sc0 sc1" : "=v"(v1) : "v"(base) : "memory");
      asm volatile("global_load_dwordx4 %0, %1, off offset:2048 sc0 sc1" : "=v"(v2) : "v"(base) : "memory");
      asm volatile("global_load_dwordx4 %0, %1, off offset:3072 sc0 sc1" : "=v"(v3) : "v"(base) : "memory");
      asm volatile("s_waitcnt vmcnt(0)" ::: "memory");
      const int r0w = wave*4;
      *(uint4v*)(hxT + ((r0w  )*1024 + ((16*l) ^ (((r0w  )&7)<<4)))) = v0;
      *(uint4v*)(hxT + ((r0w+1)*1024 + ((16*l) ^ (((r0w+1)&7)<<4)))) = v1;
      *(uint4v*)(hxT + ((r0w+2)*1024 + ((16*l) ^ (((r0w+2)&7)<<4)))) = v2;
      *(uint4v*)(hxT + ((r0w+3)*1024 + ((16*l) ^ (((r0w+3)&7)<<4)))) = v3;
    }
    __syncthreads();                                        // S1

    // ---- [B] MFMA K-loop ----
    f32x4 acc  = {0.f,0.f,0.f,0.f};
    f32x4 accq = {0.f,0.f,0.f,0.f};
    #pragma unroll
    for (int kk = 0; kk < 16; ++kk) {
      short8 bf = *(const short8*)(hxT + brow + ((kk*64 + bq16) ^ bsw));
      acc = __builtin_amdgcn_mfma_f32_16x16x32_bf16(afrag[kk], bf, acc, 0, 0, 0);
      if (hasq)
        accq = __builtin_amdgcn_mfma_f32_16x16x32_bf16(afragq[kk], bf, accq, 0, 0, 0);
    }
    {
      const int cb = n*16 + l15;
      const int r0 = q4*4;
      #pragma unroll
      for (int r = 0; r < 4; ++r)
        gacc[(m*32 + cb)*17 + r0 + r] = acc[r];
      if (hasq && q4 == 0) {
        #pragma unroll
        for (int r = 0; r < 4; ++r)
          qd[r*32 + cb] = accq[r];
      }
    }
    __syncthreads();                                        // S2

    // ---- [C] epilogue (cos fused in, per-thread) ----
    float hnew;
    {
      float q0 = cosf(sx[((size_t)t*4+0)*B_ + bglob_ep] + qd[0*32+eb]);
      float q1 = cosf(sx[((size_t)t*4+1)*B_ + bglob_ep] + qd[1*32+eb]);
      float q2 = cosf(sx[((size_t)t*4+2)*B_ + bglob_ep] + qd[2*32+eb]);
      float q3 = cosf(sx[((size_t)t*4+3)*B_ + bglob_ep] + qd[3*32+eb]);
      float fv = sig_ (q0*wfp + bfp ) + gacc[(0*32 + eb)*17 + hl];
      float iv = sig_ (q1*wip + bip ) + gacc[(1*32 + eb)*17 + hl];
      float gv = tanhf(q2*wgp + bgp_) + gacc[(2*32 + eb)*17 + hl];
      float ov = sig_ (q3*wop + bop ) + gacc[(3*32 + eb)*17 + hl];
      cxr = fv*cxr + iv*gv;
      hnew = ov * tanhf(cxr);
      hxe[eb*16 + hl] = (unsigned short)f2bf(hnew);
    }
    __syncthreads();                                        // S3: hxe ready

    if (t < T_-1) {
      // ---- [D] publish hx to LLC (sc0 sc1 write-through), then flag ----
      if (tid < 128) {
        const int b2 = tid >> 2, c4 = tid & 3;
        unsigned long long val =
          *(const unsigned long long*)((const char*)hxe + b2*32 + c4*8);
        unsigned long long addr =
          (unsigned long long)((char*)hxg + (((size_t)(bgp*BG + b2)) << 10) + (nh*16 + c4*4)*2);
        asm volatile("global_store_dwordx2 %0, %1, off sc0 sc1" :: "v"(addr), "v"(val) : "memory");
      }
      asm volatile("s_waitcnt vmcnt(0)" ::: "memory");      // per-wave drain of hxg stores
      __syncthreads();                                      // S4: all waves drained
      if (tid == 0)
        __hip_atomic_store(&flags[((size_t)t*8 + bgp)*32 + nh], 1u,
                           __ATOMIC_RELAXED, __HIP_MEMORY_SCOPE_SYSTEM);
      out[((size_t)t*B_ + bglob_ep)*H_ + h_ep] = hnew;      // overlaps the poll
      if (tid < 64) {                                       // wave0 load-polls 32 flags
        unsigned* fp = &flags[((size_t)t*8 + bgp)*32 + (tid & 31)];
        while (__hip_atomic_load(fp, __ATOMIC_RELAXED, __HIP_MEMORY_SCOPE_SYSTEM) == 0u)
          __builtin_amdgcn_s_sleep(1);
      }
      __syncthreads();                                      // S5: group step-barrier done
    } else {
      out[((size_t)t*B_ + bglob_ep)*H_ + h_ep] = hnew;
      out[(size_t)T_*B_*H_ + (size_t)bglob_ep*H_ + h_ep] = hnew;
      out[(size_t)T_*B_*H_ + (size_t)B_*H_ + (size_t)bglob_ep*H_ + h_ep] = cxr;
    }
  }
}

extern "C" void kernel_launch(void* const* d_in, const int* in_sizes, int n_in,
                              void* d_out, int out_size, void* d_ws, size_t ws_size,
                              hipStream_t stream) {
  const float* x    = (const float*)d_in[0];
  const float* Wf_l = (const float*)d_in[1];  const float* bf_l = (const float*)d_in[2];
  const float* Wf_p = (const float*)d_in[3];  const float* bf_p = (const float*)d_in[4];
  const float* Wf_r = (const float*)d_in[5];
  const float* Wi_l = (const float*)d_in[6];  const float* bi_l = (const float*)d_in[7];
  const float* Wi_p = (const float*)d_in[8];  const float* bi_p = (const float*)d_in[9];
  const float* Wi_r = (const float*)d_in[10];
  const float* Wg_l = (const float*)d_in[11]; const float* bg_l = (const float*)d_in[12];
  const float* Wg_p = (const float*)d_in[13]; const float* bg_p = (const float*)d_in[14];
  const float* Wg_r = (const float*)d_in[15];
  const float* Wo_l = (const float*)d_in[16]; const float* bo_l = (const float*)d_in[17];
  const float* Wo_p = (const float*)d_in[18]; const float* bo_p = (const float*)d_in[19];
  const float* Wo_r = (const float*)d_in[20];
  float* out = (float*)d_out;
  char*  wsb = (char*)d_ws;

  void* args[] = { &x,
                   &Wf_l, &bf_l, &Wf_p, &bf_p, &Wf_r,
                   &Wi_l, &bi_l, &Wi_p, &bi_p, &Wi_r,
                   &Wg_l, &bg_l, &Wg_p, &bg_p, &Wg_r,
                   &Wo_l, &bo_l, &Wo_p, &bo_p, &Wo_r,
                   &out, &wsb };
  hipLaunchCooperativeKernel((void*)qlstm_kernel, dim3(NB*NH), dim3(NTH),
                             args, 0, stream);
}